// Round 15
// baseline (104.880 us; speedup 1.0000x reference)
//
#include <hip/hip_runtime.h>

#define N_NODES 100000
#define N_EDGES 1600000
#define IN_DIM 256
#define OUT_DIM 32

#define CSH 10                              // coarse bucket = node >> 10
#define NSBC 98                             // ceil(100000/1024)
#define SBC 17152                           // coarse capacity (mean 16326 + 6.5 sigma)
#define EBLK 2048                           // edges per part1 block
#define NB1 ((N_EDGES + EBLK - 1) / EBLK)   // 782
#define NGB ((N_NODES + 255) / 256)         // 391 gemm blocks

typedef __attribute__((ext_vector_type(8))) short short8;
typedef __attribute__((ext_vector_type(16))) float f32x16;

#define WT_STRIDE 264    // 256 + 8 pad (bf16 elems)

__device__ inline unsigned short f2bf(float f) {
    unsigned u = __float_as_uint(f);
    unsigned r = u + 0x7FFF + ((u >> 16) & 1);   // round-to-nearest-even
    return (unsigned short)(r >> 16);
}
__device__ inline float bf2f(unsigned short us) {
    return __uint_as_float((unsigned)us << 16);
}

// ---------------------------------------------------------------------------
// K1 mega: 1173 blocks. bid%3==0 -> gemm block (391), else part1 block (782).
// part1: single-pass dual partition into 98 COARSE (1024-node) buckets.
//   77K window claims (vs 612K fine), ~21-payload windows (coalesced stores).
// gemm: h2 = bf16(x @ W), 256 rows/block, MFMA 32x32x16, norm deferred.
// ---------------------------------------------------------------------------
__global__ __launch_bounds__(512) void k_mega(const int* __restrict__ src,
                                              const int* __restrict__ dst,
                                              unsigned long long* __restrict__ qcnt,
                                              unsigned* __restrict__ gsb,
                                              unsigned short* __restrict__ gss,
                                              const float* __restrict__ x,
                                              const float* __restrict__ W,
                                              unsigned short* __restrict__ h2) {
    __shared__ __align__(16) int smemI[6 * NSBC + 2 * EBLK];   // 18784 B
    const int tid = threadIdx.x;
    const int bid = blockIdx.x;
    const int g = bid / 3;
    const int rem = bid - g * 3;

    if (rem == 0) {
        // ---------------- GEMM branch: rows [g*256, g*256+256) ----
        unsigned short* WT = (unsigned short*)smemI;   // 16896 B
        #pragma unroll
        for (int i = 0; i < 16; ++i) {
            int idx = tid + i * 512;        // k = idx>>5, c = idx&31
            WT[(idx & 31) * WT_STRIDE + (idx >> 5)] = f2bf(W[idx]);
        }
        __syncthreads();

        const int wv = tid >> 6;
        const int lane = tid & 63;
        const int col = lane & 31;
        const int hi = lane >> 5;

        const int row0 = g * 256 + wv * 32;
        int grow = row0 + col;
        int growc = grow < N_NODES ? grow : N_NODES - 1;
        const float4* xrow = reinterpret_cast<const float4*>(x + (size_t)growc * IN_DIM);

        f32x16 acc = {0.f,0.f,0.f,0.f,0.f,0.f,0.f,0.f,
                      0.f,0.f,0.f,0.f,0.f,0.f,0.f,0.f};

        #pragma unroll 4
        for (int t = 0; t < 16; ++t) {
            int k4 = t * 4 + hi * 2;        // k = t*16 + hi*8
            float4 p0 = xrow[k4];
            float4 p1 = xrow[k4 + 1];
            short8 a;
            a[0] = (short)f2bf(p0.x); a[1] = (short)f2bf(p0.y);
            a[2] = (short)f2bf(p0.z); a[3] = (short)f2bf(p0.w);
            a[4] = (short)f2bf(p1.x); a[5] = (short)f2bf(p1.y);
            a[6] = (short)f2bf(p1.z); a[7] = (short)f2bf(p1.w);
            short8 bfr = *reinterpret_cast<const short8*>(
                &WT[col * WT_STRIDE + t * 16 + hi * 8]);
            acc = __builtin_amdgcn_mfma_f32_32x32x16_bf16(a, bfr, acc, 0, 0, 0);
        }

        #pragma unroll
        for (int r = 0; r < 16; ++r) {
            int rowi = (r & 3) + 8 * (r >> 2) + 4 * hi;
            int go = row0 + rowi;
            if (go < N_NODES)
                h2[(size_t)go * OUT_DIM + col] = f2bf(acc[r]);
        }
    } else {
        // ---------------- part1 branch: 98 coarse buckets ----
        const int pb = 2 * g + rem - 1;     // 0..781
        int* histD = smemI;                 // NSBC each
        int* bbD   = smemI + NSBC;
        int* curD  = smemI + 2 * NSBC;
        int* histS = smemI + 3 * NSBC;
        int* bbS   = smemI + 4 * NSBC;
        int* curS  = smemI + 5 * NSBC;
        int* es    = smemI + 6 * NSBC;
        int* ed    = smemI + 6 * NSBC + EBLK;

        const int e0 = pb * EBLK;
        const int n = min(EBLK, N_EDGES - e0);

        if (tid < NSBC) {
            histD[tid] = 0; curD[tid] = 0; histS[tid] = 0; curS[tid] = 0;
        }
        __syncthreads();

        for (int i = tid; i < n; i += 512) {
            int s = src[e0 + i];
            int d = dst[e0 + i];
            es[i] = s; ed[i] = d;
            atomicAdd(&histD[d >> CSH], 1);
            atomicAdd(&histS[s >> CSH], 1);
        }
        __syncthreads();

        if (tid < NSBC) {
            unsigned long long pack =
                ((unsigned long long)(unsigned)histS[tid] << 32) | (unsigned)histD[tid];
            unsigned long long old = atomicAdd(&qcnt[tid], pack);
            bbD[tid] = (int)(old & 0xFFFFFFFFull);
            bbS[tid] = (int)(old >> 32);
        }
        __syncthreads();

        for (int i = tid; i < n; i += 512) {
            int d = ed[i];
            int s = es[i];
            int r = d >> CSH;
            int lp = atomicAdd(&curD[r], 1);
            int pos = bbD[r] + lp;
            if (pos < SBC)
                gsb[(size_t)r * SBC + pos] = ((unsigned)(d & 1023) << 17) | (unsigned)s;
            int rs = s >> CSH;
            int lp2 = atomicAdd(&curS[rs], 1);
            int pos2 = bbS[rs] + lp2;
            if (pos2 < SBC)
                gss[(size_t)rs * SBC + pos2] = (unsigned short)(s & 1023);
        }
    }
}

// ---------------------------------------------------------------------------
// K2 k_split: 196 blocks x 1024 thr. bid<98: private counting sort of coarse
// dst-bucket -> esrc (sorted by node) + row_ptr + deg_in. bid>=98: src-side
// histogram -> nrmtab. No cross-block coordination at all.
// ---------------------------------------------------------------------------
__global__ __launch_bounds__(1024) void k_split(const int* __restrict__ qcnt2,
                                                const unsigned* __restrict__ gsb,
                                                const unsigned short* __restrict__ gss,
                                                int* __restrict__ esrc,
                                                int* __restrict__ row_ptr,
                                                int* __restrict__ deg_in,
                                                float* __restrict__ nrmtab) {
    __shared__ int hist[1024];
    __shared__ int pref[1024];
    __shared__ int cur[1024];
    const int tid = threadIdx.x;
    const int bid = blockIdx.x;

    if (bid < NSBC) {
        const int r = bid;
        hist[tid] = 0; cur[tid] = 0;
        __syncthreads();

        int cnt = qcnt2[2 * r];
        if (cnt > SBC) cnt = SBC;
        const unsigned* bp = gsb + (size_t)r * SBC;

        for (int i = tid; i < cnt; i += 1024)
            atomicAdd(&hist[bp[i] >> 17], 1);
        __syncthreads();

        // exclusive scan (Hillis-Steele, 1024 threads)
        int v = hist[tid];
        pref[tid] = v;
        __syncthreads();
        #pragma unroll
        for (int off = 1; off < 1024; off <<= 1) {
            int t = (tid >= off) ? pref[tid - off] : 0;
            __syncthreads();
            pref[tid] += t;
            __syncthreads();
        }
        int excl = pref[tid] - v;

        const int rbase = r * SBC;
        int n = (r << CSH) + tid;
        if (n < N_NODES) {
            row_ptr[n] = rbase + excl;
            deg_in[n] = v;
        }
        pref[tid] = excl;
        __syncthreads();

        for (int i = tid; i < cnt; i += 1024) {
            unsigned pay = bp[i];
            int l = (int)(pay >> 17);
            int lp = atomicAdd(&cur[l], 1);
            esrc[rbase + pref[l] + lp] = (int)(pay & 0x1FFFF);
        }
    } else {
        const int r = bid - NSBC;
        hist[tid] = 0;
        __syncthreads();
        int cnt = qcnt2[2 * r + 1];
        if (cnt > SBC) cnt = SBC;
        const unsigned short* sp = gss + (size_t)r * SBC;
        for (int i = tid; i < cnt; i += 1024)
            atomicAdd(&hist[sp[i]], 1);
        __syncthreads();
        int n = (r << CSH) + tid;
        if (n < N_NODES) {
            int dg = hist[tid];
            nrmtab[n] = rsqrtf((float)(dg > 1 ? dg : 1));
        }
    }
}

// ---------------------------------------------------------------------------
// K3 k_gather: pure gather on sorted esrc. 8 thr/node, unroll 4, bf16 h2.
// ---------------------------------------------------------------------------
__global__ __launch_bounds__(512) void k_gather(const int* __restrict__ esrc,
                                                const int* __restrict__ row_ptr,
                                                const int* __restrict__ deg_in,
                                                const unsigned short* __restrict__ h2,
                                                const float* __restrict__ nrmtab,
                                                const float* __restrict__ bias,
                                                float* __restrict__ out) {
    const int tid = threadIdx.x;
    const int q = tid & 7;
    const int nl = tid >> 3;
    const float4 bb = reinterpret_cast<const float4*>(bias)[q];

    #pragma unroll
    for (int sweep = 0; sweep < 2; ++sweep) {
        int node = blockIdx.x * 128 + sweep * 64 + nl;
        if (node >= N_NODES) continue;
        int st = row_ptr[node];
        int deg = deg_in[node];
        float4 acc = make_float4(0.f, 0.f, 0.f, 0.f);
        int j = 0;
        for (; j + 4 <= deg; j += 4) {
            int s0 = esrc[st + j + 0];
            int s1 = esrc[st + j + 1];
            int s2 = esrc[st + j + 2];
            int s3 = esrc[st + j + 3];
            float w0 = nrmtab[s0];
            float w1 = nrmtab[s1];
            float w2 = nrmtab[s2];
            float w3 = nrmtab[s3];
            ushort4 a0 = *reinterpret_cast<const ushort4*>(&h2[(size_t)s0 * OUT_DIM + q * 4]);
            ushort4 a1 = *reinterpret_cast<const ushort4*>(&h2[(size_t)s1 * OUT_DIM + q * 4]);
            ushort4 a2 = *reinterpret_cast<const ushort4*>(&h2[(size_t)s2 * OUT_DIM + q * 4]);
            ushort4 a3 = *reinterpret_cast<const ushort4*>(&h2[(size_t)s3 * OUT_DIM + q * 4]);
            acc.x += bf2f(a0.x) * w0 + bf2f(a1.x) * w1 + bf2f(a2.x) * w2 + bf2f(a3.x) * w3;
            acc.y += bf2f(a0.y) * w0 + bf2f(a1.y) * w1 + bf2f(a2.y) * w2 + bf2f(a3.y) * w3;
            acc.z += bf2f(a0.z) * w0 + bf2f(a1.z) * w1 + bf2f(a2.z) * w2 + bf2f(a3.z) * w3;
            acc.w += bf2f(a0.w) * w0 + bf2f(a1.w) * w1 + bf2f(a2.w) * w2 + bf2f(a3.w) * w3;
        }
        for (; j < deg; ++j) {
            int s = esrc[st + j];
            float w = nrmtab[s];
            ushort4 a = *reinterpret_cast<const ushort4*>(&h2[(size_t)s * OUT_DIM + q * 4]);
            acc.x += bf2f(a.x) * w; acc.y += bf2f(a.y) * w;
            acc.z += bf2f(a.z) * w; acc.w += bf2f(a.w) * w;
        }
        float nrm = rsqrtf((float)(deg > 1 ? deg : 1));
        float4 o = make_float4(acc.x * nrm + bb.x, acc.y * nrm + bb.y,
                               acc.z * nrm + bb.z, acc.w * nrm + bb.w);
        reinterpret_cast<float4*>(out)[(size_t)node * 8 + q] = o;
    }
}

// ---------------------------------------------------------------------------
extern "C" void kernel_launch(void* const* d_in, const int* in_sizes, int n_in,
                              void* d_out, int out_size, void* d_ws, size_t ws_size,
                              hipStream_t stream) {
    const float* x   = (const float*)d_in[0];
    const int*   src = (const int*)d_in[1];
    const int*   dst = (const int*)d_in[2];
    const float* W   = (const float*)d_in[3];
    const float* b   = (const float*)d_in[4];
    float* out = (float*)d_out;

    // ws bytes: nrmtab f32[N] @0 | row_ptr @400000 | deg_in @800000 |
    //           qcnt u64[98] @1200000 | h2 bf16[N*32] @1200800 |
    //           gsb u32[98*SBC] | gss u16[98*SBC] | esrc i32[98*SBC]
    float* nrmtab = (float*)d_ws;
    int* row_ptr  = (int*)((char*)d_ws + 400000);
    int* deg_in   = (int*)((char*)d_ws + 800000);
    unsigned long long* qcnt = (unsigned long long*)((char*)d_ws + 1200000);
    int* qcnt2    = (int*)qcnt;
    unsigned short* h2 = (unsigned short*)((char*)d_ws + 1200800);
    unsigned* gsb = (unsigned*)((char*)d_ws + 7600800);
    unsigned short* gss = (unsigned short*)((char*)d_ws + 14324384);
    int* esrc     = (int*)((char*)d_ws + 17686176);

    hipMemsetAsync(qcnt, 0, NSBC * sizeof(unsigned long long), stream);

    k_mega<<<NB1 + NGB, 512, 0, stream>>>(src, dst, qcnt, gsb, gss, x, W, h2);

    k_split<<<2 * NSBC, 1024, 0, stream>>>(qcnt2, gsb, gss, esrc, row_ptr, deg_in, nrmtab);

    k_gather<<<(N_NODES + 127) / 128, 512, 0, stream>>>(esrc, row_ptr, deg_in, h2, nrmtab, b, out);
}

// Round 16
// 90.116 us; speedup vs baseline: 1.1638x; 1.1638x over previous
//
#include <hip/hip_runtime.h>

#define N_NODES 100000
#define N_EDGES 1600000
#define IN_DIM 256
#define OUT_DIM 32

#define SB_SHIFT 7                          // bucket = node >> 7 (128 nodes)
#define NSB ((N_NODES + 127) >> 7)          // 782
#define SBCAP 2368                          // mean 2046 + ~7 sigma
#define NB1 782                             // part1 blocks (512 thr x 4 edges = 2048)
#define NGB ((N_NODES + 255) / 256)         // 391 gemm blocks
#define NI4 (N_EDGES / 4)                   // 400000 int4 edge-quads

typedef __attribute__((ext_vector_type(8))) short short8;
typedef __attribute__((ext_vector_type(16))) float f32x16;

#define WT_STRIDE 264    // 256 + 8 pad (bf16 elems)

__device__ inline unsigned short f2bf(float f) {
    unsigned u = __float_as_uint(f);
    unsigned r = u + 0x7FFF + ((u >> 16) & 1);   // round-to-nearest-even
    return (unsigned short)(r >> 16);
}
__device__ inline float bf2f(unsigned short us) {
    return __uint_as_float((unsigned)us << 16);
}

// ---------------------------------------------------------------------------
// K1 mega: 1173 blocks. bid%3==0 -> gemm block (391), else part1 block (782).
// part1 (R16): int4 edge loads (2 VMEM ops/thread), edges held in REGISTERS
// across the claim barriers -- no LDS staging at all. LDS = 6x782 ints.
// gemm: h2 = bf16(x @ W), 256 rows/block, MFMA 32x32x16, norm deferred.
// ---------------------------------------------------------------------------
__global__ __launch_bounds__(512) void k_mega(const int* __restrict__ src,
                                              const int* __restrict__ dst,
                                              unsigned long long* __restrict__ qcnt,
                                              unsigned* __restrict__ gsb,
                                              unsigned char* __restrict__ gss,
                                              const float* __restrict__ x,
                                              const float* __restrict__ W,
                                              unsigned short* __restrict__ h2) {
    __shared__ __align__(16) int smemI[6 * NSB];   // 18768 B (gemm uses 16896)
    const int tid = threadIdx.x;
    const int bid = blockIdx.x;
    const int g = bid / 3;
    const int rem = bid - g * 3;

    if (rem == 0) {
        // ---------------- GEMM branch: rows [g*256, g*256+256) ----
        unsigned short* WT = (unsigned short*)smemI;   // 16896 B
        #pragma unroll
        for (int i = 0; i < 16; ++i) {
            int idx = tid + i * 512;        // k = idx>>5, c = idx&31
            WT[(idx & 31) * WT_STRIDE + (idx >> 5)] = f2bf(W[idx]);
        }
        __syncthreads();

        const int wv = tid >> 6;
        const int lane = tid & 63;
        const int col = lane & 31;
        const int hi = lane >> 5;

        const int row0 = g * 256 + wv * 32;
        int grow = row0 + col;
        int growc = grow < N_NODES ? grow : N_NODES - 1;
        const float4* xrow = reinterpret_cast<const float4*>(x + (size_t)growc * IN_DIM);

        f32x16 acc = {0.f,0.f,0.f,0.f,0.f,0.f,0.f,0.f,
                      0.f,0.f,0.f,0.f,0.f,0.f,0.f,0.f};

        #pragma unroll 4
        for (int t = 0; t < 16; ++t) {
            int k4 = t * 4 + hi * 2;        // k = t*16 + hi*8
            float4 p0 = xrow[k4];
            float4 p1 = xrow[k4 + 1];
            short8 a;
            a[0] = (short)f2bf(p0.x); a[1] = (short)f2bf(p0.y);
            a[2] = (short)f2bf(p0.z); a[3] = (short)f2bf(p0.w);
            a[4] = (short)f2bf(p1.x); a[5] = (short)f2bf(p1.y);
            a[6] = (short)f2bf(p1.z); a[7] = (short)f2bf(p1.w);
            short8 bfr = *reinterpret_cast<const short8*>(
                &WT[col * WT_STRIDE + t * 16 + hi * 8]);
            acc = __builtin_amdgcn_mfma_f32_32x32x16_bf16(a, bfr, acc, 0, 0, 0);
        }

        #pragma unroll
        for (int r = 0; r < 16; ++r) {
            int rowi = (r & 3) + 8 * (r >> 2) + 4 * hi;
            int go = row0 + rowi;
            if (go < N_NODES)
                h2[(size_t)go * OUT_DIM + col] = f2bf(acc[r]);
        }
    } else {
        // ---------------- part1 branch: registers-only dual partition ----
        const int pb = 2 * g + rem - 1;     // 0..781
        int* histD = smemI;                 // NSB each
        int* bbD   = smemI + NSB;
        int* curD  = smemI + 2 * NSB;
        int* histS = smemI + 3 * NSB;
        int* bbS   = smemI + 4 * NSB;
        int* curS  = smemI + 5 * NSB;

        for (int i = tid; i < NSB; i += 512) {
            histD[i] = 0; curD[i] = 0; histS[i] = 0; curS[i] = 0;
        }
        __syncthreads();

        const int gid = pb * 512 + tid;     // int4 index
        const bool valid = gid < NI4;
        int4 sv, dv;
        if (valid) {
            sv = reinterpret_cast<const int4*>(src)[gid];
            dv = reinterpret_cast<const int4*>(dst)[gid];
            atomicAdd(&histD[dv.x >> SB_SHIFT], 1);
            atomicAdd(&histD[dv.y >> SB_SHIFT], 1);
            atomicAdd(&histD[dv.z >> SB_SHIFT], 1);
            atomicAdd(&histD[dv.w >> SB_SHIFT], 1);
            atomicAdd(&histS[sv.x >> SB_SHIFT], 1);
            atomicAdd(&histS[sv.y >> SB_SHIFT], 1);
            atomicAdd(&histS[sv.z >> SB_SHIFT], 1);
            atomicAdd(&histS[sv.w >> SB_SHIFT], 1);
        }
        __syncthreads();

        for (int i = tid; i < NSB; i += 512) {
            unsigned long long pack =
                ((unsigned long long)(unsigned)histS[i] << 32) | (unsigned)histD[i];
            unsigned long long old = atomicAdd(&qcnt[i], pack);
            bbD[i] = (int)(old & 0xFFFFFFFFull);
            bbS[i] = (int)(old >> 32);
        }
        __syncthreads();

        if (valid) {
            int ss[4] = {sv.x, sv.y, sv.z, sv.w};
            int dd[4] = {dv.x, dv.y, dv.z, dv.w};
            #pragma unroll
            for (int u = 0; u < 4; ++u) {
                int d = dd[u], s = ss[u];
                int r = d >> SB_SHIFT;
                int lp = atomicAdd(&curD[r], 1);
                int pos = bbD[r] + lp;
                if (pos < SBCAP)
                    gsb[(size_t)r * SBCAP + pos] =
                        ((unsigned)(d & 127) << 17) | (unsigned)s;
                int rs = s >> SB_SHIFT;
                int lp2 = atomicAdd(&curS[rs], 1);
                int pos2 = bbS[rs] + lp2;
                if (pos2 < SBCAP)
                    gss[(size_t)rs * SBCAP + pos2] = (unsigned char)(s & 127);
            }
        }
    }
}

// ---------------------------------------------------------------------------
// K2: per-bucket u8 histogram (128 bins) -> nrm_src table
// ---------------------------------------------------------------------------
__global__ __launch_bounds__(256) void k_deg2(const int* __restrict__ qcnt2,
                                              const unsigned char* __restrict__ gss,
                                              float* __restrict__ nrmtab) {
    __shared__ int hist[128];
    const int r = blockIdx.x;
    const int tid = threadIdx.x;
    if (tid < 128) hist[tid] = 0;
    __syncthreads();
    int cnt = qcnt2[2 * r + 1];
    if (cnt > SBCAP) cnt = SBCAP;
    const unsigned char* bp = gss + (size_t)r * SBCAP;
    for (int i = tid; i < cnt; i += 256)
        atomicAdd(&hist[bp[i]], 1);
    __syncthreads();
    if (tid < 128) {
        int nn = (r << SB_SHIFT) + tid;
        if (nn < N_NODES) {
            int dg = hist[tid];
            nrmtab[nn] = rsqrtf((float)(dg > 1 ? dg : 1));
        }
    }
}

// ---------------------------------------------------------------------------
// K3: per-bucket sort + gather (bf16 h2, unroll 4). Bucket = 128 nodes.
// Each edge's h2 row is ONE 64B line shared by its 8 q-threads.
// ---------------------------------------------------------------------------
__global__ __launch_bounds__(512) void k_combo2(const int* __restrict__ qcnt2,
                                                const unsigned* __restrict__ gsb,
                                                const unsigned short* __restrict__ h2,
                                                const float* __restrict__ nrmtab,
                                                const float* __restrict__ bias,
                                                float* __restrict__ out) {
    __shared__ unsigned pstage[SBCAP];   // 9472 B
    __shared__ int esl[SBCAP];           // 9472 B
    __shared__ int hist[128];
    __shared__ int pref[128];
    __shared__ int cur[128];

    const int r = blockIdx.x;
    const int tid = threadIdx.x;

    if (tid < 128) { hist[tid] = 0; cur[tid] = 0; }
    int cnt = qcnt2[2 * r];
    if (cnt > SBCAP) cnt = SBCAP;
    const unsigned* bp = gsb + (size_t)r * SBCAP;
    __syncthreads();

    for (int i = tid; i < cnt; i += 512) {
        unsigned pay = bp[i];
        pstage[i] = pay;
        atomicAdd(&hist[pay >> 17], 1);
    }
    __syncthreads();

    int v = 0;
    if (tid < 128) { v = hist[tid]; pref[tid] = v; }
    __syncthreads();
    #pragma unroll
    for (int off = 1; off < 128; off <<= 1) {
        int t = (tid < 128 && tid >= off) ? pref[tid - off] : 0;
        __syncthreads();
        if (tid < 128) pref[tid] += t;
        __syncthreads();
    }
    if (tid < 128) pref[tid] -= v;
    __syncthreads();

    for (int i = tid; i < cnt; i += 512) {
        unsigned pay = pstage[i];
        int l = (int)(pay >> 17);
        int lp = atomicAdd(&cur[l], 1);
        esl[pref[l] + lp] = (int)(pay & 0x1FFFF);
    }
    __syncthreads();

    const int q = tid & 7;
    const int nl = tid >> 3;
    const float4 bb = reinterpret_cast<const float4*>(bias)[q];
    #pragma unroll
    for (int sweep = 0; sweep < 2; ++sweep) {
        int l = sweep * 64 + nl;          // 0..127
        int st = pref[l];
        int deg = hist[l];
        float4 acc = make_float4(0.f, 0.f, 0.f, 0.f);
        int j = 0;
        for (; j + 4 <= deg; j += 4) {
            int s0 = esl[st + j + 0];
            int s1 = esl[st + j + 1];
            int s2 = esl[st + j + 2];
            int s3 = esl[st + j + 3];
            float w0 = nrmtab[s0];
            float w1 = nrmtab[s1];
            float w2 = nrmtab[s2];
            float w3 = nrmtab[s3];
            ushort4 a0 = *reinterpret_cast<const ushort4*>(&h2[(size_t)s0 * OUT_DIM + q * 4]);
            ushort4 a1 = *reinterpret_cast<const ushort4*>(&h2[(size_t)s1 * OUT_DIM + q * 4]);
            ushort4 a2 = *reinterpret_cast<const ushort4*>(&h2[(size_t)s2 * OUT_DIM + q * 4]);
            ushort4 a3 = *reinterpret_cast<const ushort4*>(&h2[(size_t)s3 * OUT_DIM + q * 4]);
            acc.x += bf2f(a0.x) * w0 + bf2f(a1.x) * w1 + bf2f(a2.x) * w2 + bf2f(a3.x) * w3;
            acc.y += bf2f(a0.y) * w0 + bf2f(a1.y) * w1 + bf2f(a2.y) * w2 + bf2f(a3.y) * w3;
            acc.z += bf2f(a0.z) * w0 + bf2f(a1.z) * w1 + bf2f(a2.z) * w2 + bf2f(a3.z) * w3;
            acc.w += bf2f(a0.w) * w0 + bf2f(a1.w) * w1 + bf2f(a2.w) * w2 + bf2f(a3.w) * w3;
        }
        for (; j < deg; ++j) {
            int s = esl[st + j];
            float w = nrmtab[s];
            ushort4 a = *reinterpret_cast<const ushort4*>(&h2[(size_t)s * OUT_DIM + q * 4]);
            acc.x += bf2f(a.x) * w; acc.y += bf2f(a.y) * w;
            acc.z += bf2f(a.z) * w; acc.w += bf2f(a.w) * w;
        }
        int node = (r << SB_SHIFT) + l;
        if (node < N_NODES) {
            float nrm = rsqrtf((float)(deg > 1 ? deg : 1));
            float4 o = make_float4(acc.x * nrm + bb.x, acc.y * nrm + bb.y,
                                   acc.z * nrm + bb.z, acc.w * nrm + bb.w);
            reinterpret_cast<float4*>(out)[(size_t)node * 8 + q] = o;
        }
    }
}

// ---------------------------------------------------------------------------
extern "C" void kernel_launch(void* const* d_in, const int* in_sizes, int n_in,
                              void* d_out, int out_size, void* d_ws, size_t ws_size,
                              hipStream_t stream) {
    const float* x   = (const float*)d_in[0];
    const int*   src = (const int*)d_in[1];
    const int*   dst = (const int*)d_in[2];
    const float* W   = (const float*)d_in[3];
    const float* b   = (const float*)d_in[4];
    float* out = (float*)d_out;

    // ws bytes: nrmtab f32[N] @0 | qcnt u64[NSB] @400000 | h2 bf16[N*32] @406272 |
    //           gsb u32[NSB*SBCAP] @6806272 | gss u8[NSB*SBCAP] @14213376
    float* nrmtab = (float*)d_ws;
    unsigned long long* qcnt = (unsigned long long*)((char*)d_ws + 400000);
    int* qcnt2 = (int*)qcnt;
    unsigned short* h2 = (unsigned short*)((char*)d_ws + 406272);
    unsigned* gsb = (unsigned*)((char*)d_ws + 6806272);
    unsigned char* gss = (unsigned char*)((char*)d_ws + 14213376);

    hipMemsetAsync(qcnt, 0, NSB * sizeof(unsigned long long), stream);

    k_mega<<<NB1 + NGB, 512, 0, stream>>>(src, dst, qcnt, gsb, gss, x, W, h2);

    k_deg2<<<NSB, 256, 0, stream>>>(qcnt2, gss, nrmtab);

    k_combo2<<<NSB, 512, 0, stream>>>(qcnt2, gsb, h2, nrmtab, b, out);
}